// Round 2
// 2889.240 us; speedup vs baseline: 1.0854x; 1.0854x over previous
//
#include <hip/hip_runtime.h>

#define D 128
#define N_ITEMS 200000
#define N_USERS 100000
#define TI 64    // items per score-kernel tile
#define ST 132   // Tt row stride in floats (multiple of 4 for float4 stores)

#define INV_SQRT_D 0.088388347648318447f

// ---------------------------------------------------------------------------
// CSR build: histogram -> 3-kernel exclusive scan -> scatter pairs
// ---------------------------------------------------------------------------
__global__ __launch_bounds__(256) void hist_kernel(
    const int* __restrict__ dst, unsigned* __restrict__ counts, int E)
{
    int e = blockIdx.x * 256 + threadIdx.x;
    if (e < E) atomicAdd(&counts[dst[e]], 1u);
}

__global__ __launch_bounds__(256) void scan1_kernel(
    const unsigned* __restrict__ counts, unsigned* __restrict__ offsets,
    unsigned* __restrict__ blocksums, int n)
{
    __shared__ unsigned s[256];
    int tid = threadIdx.x;
    int i = blockIdx.x * 256 + tid;
    unsigned v = (i < n) ? counts[i] : 0u;
    s[tid] = v; __syncthreads();
    #pragma unroll
    for (int off = 1; off < 256; off <<= 1) {
        unsigned t = (tid >= off) ? s[tid - off] : 0u;
        __syncthreads();
        s[tid] += t;
        __syncthreads();
    }
    if (i < n) offsets[i] = s[tid] - v;          // exclusive within block
    if (tid == 255) blocksums[blockIdx.x] = s[255];
}

__global__ __launch_bounds__(1024) void scan2_kernel(
    unsigned* __restrict__ blocksums, int nb)
{
    __shared__ unsigned s[1024];
    int tid = threadIdx.x;
    unsigned v = (tid < nb) ? blocksums[tid] : 0u;
    s[tid] = v; __syncthreads();
    #pragma unroll
    for (int off = 1; off < 1024; off <<= 1) {
        unsigned t = (tid >= off) ? s[tid - off] : 0u;
        __syncthreads();
        s[tid] += t;
        __syncthreads();
    }
    if (tid < nb) blocksums[tid] = s[tid] - v;   // exclusive
}

__global__ __launch_bounds__(256) void scan3_kernel(
    unsigned* __restrict__ offsets, unsigned* __restrict__ cursor,
    const unsigned* __restrict__ blocksums, int n, unsigned Etot)
{
    int i = blockIdx.x * 256 + threadIdx.x;
    if (i < n) {
        unsigned o = offsets[i] + blocksums[blockIdx.x];
        offsets[i] = o;
        cursor[i] = o;
    }
    if (i == 0) offsets[n] = Etot;
}

__global__ __launch_bounds__(256) void scatter_kernel(
    const int* __restrict__ src, const int* __restrict__ dst,
    const float* __restrict__ val, unsigned* __restrict__ cursor,
    int2* __restrict__ pairs, int E)
{
    int e = blockIdx.x * 256 + threadIdx.x;
    if (e >= E) return;
    unsigned pos = atomicAdd(&cursor[dst[e]], 1u);
    pairs[pos] = make_int2(src[e], __float_as_int(val[e]));
}

// ---------------------------------------------------------------------------
// Gather spmm: one 32-lane group per dst row; register accumulation; one
// coalesced non-atomic float4 store per lane. No pre-zeroing needed.
// ---------------------------------------------------------------------------
__global__ __launch_bounds__(256) void gather_spmm_kernel(
    const unsigned* __restrict__ offsets, const int2* __restrict__ pairs,
    const float4* __restrict__ x4, float4* __restrict__ out4, int nrows)
{
    int row = blockIdx.x * 8 + (threadIdx.x >> 5);
    if (row >= nrows) return;
    int lane = threadIdx.x & 31;
    unsigned j = offsets[row], end = offsets[row + 1];
    float4 acc = make_float4(0.f, 0.f, 0.f, 0.f);
    for (; j + 2 <= end; j += 2) {
        int2 p0 = pairs[j];
        int2 p1 = pairs[j + 1];
        float4 a = x4[(size_t)p0.x * 32 + lane];
        float4 b = x4[(size_t)p1.x * 32 + lane];
        float v0 = __int_as_float(p0.y), v1 = __int_as_float(p1.y);
        acc.x = fmaf(v0, a.x, acc.x); acc.y = fmaf(v0, a.y, acc.y);
        acc.z = fmaf(v0, a.z, acc.z); acc.w = fmaf(v0, a.w, acc.w);
        acc.x = fmaf(v1, b.x, acc.x); acc.y = fmaf(v1, b.y, acc.y);
        acc.z = fmaf(v1, b.z, acc.z); acc.w = fmaf(v1, b.w, acc.w);
    }
    if (j < end) {
        int2 p0 = pairs[j];
        float4 a = x4[(size_t)p0.x * 32 + lane];
        float v0 = __int_as_float(p0.y);
        acc.x = fmaf(v0, a.x, acc.x); acc.y = fmaf(v0, a.y, acc.y);
        acc.z = fmaf(v0, a.z, acc.z); acc.w = fmaf(v0, a.w, acc.w);
    }
    out4[(size_t)row * 32 + lane] = acc;
}

// ---------------------------------------------------------------------------
// Fused gated-attention score + softmax + weighted-combine kernel.
//   - I matrices read straight from global (L1/L2-resident, 64KB each);
//     LDS holds only the x*nb tile -> 34 KB -> 4 blocks/CU (was 82KB -> 1).
//   - Tt stored row-major [TI][ST]: float4 staging writes are contiguous
//     (conflict-free); k-loop reads are 16-lane broadcasts (<=2-way, free).
//   - per-thread tile: 4 items x 8 cols = 32 accumulators of ILP.
//   - combine fused: weights in LDS, neighbor written in place over nb0.
// ---------------------------------------------------------------------------
__global__ __launch_bounds__(256, 4) void score_combine_kernel(
    const float4* __restrict__ x4,
    float4* __restrict__ nb0,                       // in: nb_in, out: neighbor
    const float4* __restrict__ nb1, const float4* __restrict__ nb2,
    const float4* __restrict__ I0, const float4* __restrict__ I1,
    const float4* __restrict__ I2)
{
    __shared__ __align__(16) float Tt[TI * ST];     // 33792 B
    __shared__ float Wl[TI * 3];                    // 768 B
    const int tid = threadIdx.x;
    const int jg = tid & 15;          // 16 groups cover 128 cols, 8 each
    const int ig = tid >> 4;          // 16 groups cover 64 items, 4 each
    const int i0 = ig << 2;
    const int itemBase = blockIdx.x * TI;

    const float4* nbs[3] = {(const float4*)nb0, nb1, nb2};
    const float4* Is[3]  = {I0, I1, I2};
    float sreg[3][4];

    #pragma unroll
    for (int rel = 0; rel < 3; ++rel) {
        __syncthreads();
        // ---- stage Tt = x * nb, row-major [il][dd], stride ST ----
        const float4* nbp = nbs[rel];
        #pragma unroll
        for (int it = 0; it < 8; ++it) {
            int f4 = it * 256 + tid;
            int il = f4 >> 5, dd4 = f4 & 31;
            size_t g = (size_t)(itemBase + il) * 32 + dd4;
            float4 a = x4[g], b = nbp[g];
            float4 p;
            p.x = a.x * b.x; p.y = a.y * b.y;
            p.z = a.z * b.z; p.w = a.w * b.w;
            *(float4*)&Tt[il * ST + (dd4 << 2)] = p;
        }
        __syncthreads();

        // ---- h = Tt @ I, leaky, row-sum ----
        const float4* Ip = Is[rel];
        float acc[4][8];
        #pragma unroll
        for (int a = 0; a < 4; ++a)
            #pragma unroll
            for (int b = 0; b < 8; ++b) acc[a][b] = 0.f;

        const float* t0 = &Tt[(i0 + 0) * ST];
        const float* t1 = &Tt[(i0 + 1) * ST];
        const float* t2 = &Tt[(i0 + 2) * ST];
        const float* t3 = &Tt[(i0 + 3) * ST];

        #pragma unroll 4
        for (int k = 0; k < D; ++k) {
            float4 iv0 = Ip[k * 32 + (jg << 1)];
            float4 iv1 = Ip[k * 32 + (jg << 1) + 1];
            float tv0 = t0[k], tv1 = t1[k], tv2 = t2[k], tv3 = t3[k];
            acc[0][0] = fmaf(tv0, iv0.x, acc[0][0]);
            acc[0][1] = fmaf(tv0, iv0.y, acc[0][1]);
            acc[0][2] = fmaf(tv0, iv0.z, acc[0][2]);
            acc[0][3] = fmaf(tv0, iv0.w, acc[0][3]);
            acc[0][4] = fmaf(tv0, iv1.x, acc[0][4]);
            acc[0][5] = fmaf(tv0, iv1.y, acc[0][5]);
            acc[0][6] = fmaf(tv0, iv1.z, acc[0][6]);
            acc[0][7] = fmaf(tv0, iv1.w, acc[0][7]);
            acc[1][0] = fmaf(tv1, iv0.x, acc[1][0]);
            acc[1][1] = fmaf(tv1, iv0.y, acc[1][1]);
            acc[1][2] = fmaf(tv1, iv0.z, acc[1][2]);
            acc[1][3] = fmaf(tv1, iv0.w, acc[1][3]);
            acc[1][4] = fmaf(tv1, iv1.x, acc[1][4]);
            acc[1][5] = fmaf(tv1, iv1.y, acc[1][5]);
            acc[1][6] = fmaf(tv1, iv1.z, acc[1][6]);
            acc[1][7] = fmaf(tv1, iv1.w, acc[1][7]);
            acc[2][0] = fmaf(tv2, iv0.x, acc[2][0]);
            acc[2][1] = fmaf(tv2, iv0.y, acc[2][1]);
            acc[2][2] = fmaf(tv2, iv0.z, acc[2][2]);
            acc[2][3] = fmaf(tv2, iv0.w, acc[2][3]);
            acc[2][4] = fmaf(tv2, iv1.x, acc[2][4]);
            acc[2][5] = fmaf(tv2, iv1.y, acc[2][5]);
            acc[2][6] = fmaf(tv2, iv1.z, acc[2][6]);
            acc[2][7] = fmaf(tv2, iv1.w, acc[2][7]);
            acc[3][0] = fmaf(tv3, iv0.x, acc[3][0]);
            acc[3][1] = fmaf(tv3, iv0.y, acc[3][1]);
            acc[3][2] = fmaf(tv3, iv0.z, acc[3][2]);
            acc[3][3] = fmaf(tv3, iv0.w, acc[3][3]);
            acc[3][4] = fmaf(tv3, iv1.x, acc[3][4]);
            acc[3][5] = fmaf(tv3, iv1.y, acc[3][5]);
            acc[3][6] = fmaf(tv3, iv1.z, acc[3][6]);
            acc[3][7] = fmaf(tv3, iv1.w, acc[3][7]);
        }

        #pragma unroll
        for (int a = 0; a < 4; ++a) {
            float s = 0.f;
            #pragma unroll
            for (int b = 0; b < 8; ++b) {
                float h = acc[a][b];
                s += (h >= 0.f) ? h : 0.2f * h;
            }
            #pragma unroll
            for (int off = 8; off; off >>= 1)
                s += __shfl_down(s, off, 16);
            sreg[rel][a] = s * INV_SQRT_D;
        }
    }

    // ---- softmax over relations -> LDS weights ----
    if (jg == 0) {
        #pragma unroll
        for (int a = 0; a < 4; ++a) {
            float s0 = sreg[0][a], s1 = sreg[1][a], s2 = sreg[2][a];
            float m = fmaxf(s0, fmaxf(s1, s2));
            float e0 = expf(s0 - m), e1 = expf(s1 - m), e2 = expf(s2 - m);
            float inv = 1.f / (e0 + e1 + e2);
            int il = i0 + a;
            Wl[il * 3 + 0] = e0 * inv;
            Wl[il * 3 + 1] = e1 * inv;
            Wl[il * 3 + 2] = e2 * inv;
        }
    }
    __syncthreads();

    // ---- fused weighted combine, in place over nb0 ----
    #pragma unroll
    for (int it = 0; it < 8; ++it) {
        int f4 = it * 256 + tid;
        int il = f4 >> 5, dd4 = f4 & 31;
        size_t g = (size_t)(itemBase + il) * 32 + dd4;
        float w0 = Wl[il * 3 + 0], w1 = Wl[il * 3 + 1], w2 = Wl[il * 3 + 2];
        float4 a = nb0[g], b = nb1[g], c = nb2[g];
        float4 r;
        r.x = fmaf(w0, a.x, fmaf(w1, b.x, w2 * c.x));
        r.y = fmaf(w0, a.y, fmaf(w1, b.y, w2 * c.y));
        r.z = fmaf(w0, a.z, fmaf(w1, b.z, w2 * c.z));
        r.w = fmaf(w0, a.w, fmaf(w1, b.w, w2 * c.w));
        nb0[g] = r;
    }
}

extern "C" void kernel_launch(void* const* d_in, const int* in_sizes, int n_in,
                              void* d_out, int out_size, void* d_ws, size_t ws_size,
                              hipStream_t stream) {
    const float* x       = (const float*)d_in[1];
    const int*   src0    = (const int*)d_in[2];
    const int*   dst0    = (const int*)d_in[3];
    const float* val0    = (const float*)d_in[4];
    const int*   src1    = (const int*)d_in[5];
    const int*   dst1    = (const int*)d_in[6];
    const float* val1    = (const float*)d_in[7];
    const int*   src2    = (const int*)d_in[8];
    const int*   dst2    = (const int*)d_in[9];
    const float* val2    = (const float*)d_in[10];
    const int*   src_ui  = (const int*)d_in[11];
    const int*   dst_ui  = (const int*)d_in[12];
    const float* val_ui  = (const float*)d_in[13];
    const float* I0      = (const float*)d_in[14];
    const float* I1      = (const float*)d_in[15];
    const float* I2      = (const float*)d_in[16];

    const int E_ii = in_sizes[2];
    const int E_ui = in_sizes[11];

    float* u_emb = (float*)d_out;                          // [N_USERS*D], written last
    float* nb0   = (float*)d_out + (size_t)N_USERS * D;    // neighbor slot doubles as nb_in

    // workspace layout
    float*    nb1       = (float*)d_ws;                                  // 25.6M floats
    float*    nb2       = nb1 + (size_t)N_ITEMS * D;                     // 25.6M floats
    unsigned* cc        = (unsigned*)(nb2 + (size_t)N_ITEMS * D);        // counts/cursor [N_ITEMS]
    unsigned* offsets   = cc + N_ITEMS;                                  // [N_ITEMS+1]
    unsigned* blocksums = offsets + N_ITEMS + 1;                         // [1024]
    uintptr_t pu        = ((uintptr_t)(blocksums + 1024) + 15) & ~(uintptr_t)15;
    int2*     pairs_ui  = (int2*)pu;                                     // [E_ui]
    // ii pairs live in the u_emb output region (free until the final ui gather)
    int2*     pairs_ii  = (int2*)d_out;                                  // 25.6 MB <= 51.2 MB region

    auto build_and_gather = [&](const int* src, const int* dst, const float* val,
                                int E, int nrows, int2* pairs, float* out) {
        hipMemsetAsync(cc, 0, (size_t)nrows * sizeof(unsigned), stream);
        int gE = (E + 255) / 256;
        int gN = (nrows + 255) / 256;
        hist_kernel<<<gE, 256, 0, stream>>>(dst, cc, E);
        scan1_kernel<<<gN, 256, 0, stream>>>(cc, offsets, blocksums, nrows);
        scan2_kernel<<<1, 1024, 0, stream>>>(blocksums, gN);
        scan3_kernel<<<gN, 256, 0, stream>>>(offsets, cc, blocksums, nrows, (unsigned)E);
        scatter_kernel<<<gE, 256, 0, stream>>>(src, dst, val, cc, pairs, E);
        gather_spmm_kernel<<<(nrows + 7) / 8, 256, 0, stream>>>(
            offsets, pairs, (const float4*)x, (float4*)out, nrows);
    };

    // item-item relations (pairs scratch in u_emb region)
    build_and_gather(src0, dst0, val0, E_ii, N_ITEMS, pairs_ii, nb0);
    build_and_gather(src1, dst1, val1, E_ii, N_ITEMS, pairs_ii, nb1);
    build_and_gather(src2, dst2, val2, E_ii, N_ITEMS, pairs_ii, nb2);

    // fused score + softmax + combine (in-place over nb0 == neighbor output)
    score_combine_kernel<<<N_ITEMS / TI, 256, 0, stream>>>(
        (const float4*)x, (float4*)nb0, (const float4*)nb1, (const float4*)nb2,
        (const float4*)I0, (const float4*)I1, (const float4*)I2);

    // user-item last (writes u_emb region, whose pairs scratch is now dead)
    build_and_gather(src_ui, dst_ui, val_ui, E_ui, N_USERS, pairs_ui, u_emb);
}

// Round 3
// 2558.357 us; speedup vs baseline: 1.2258x; 1.1293x over previous
//
#include <hip/hip_runtime.h>

#define D 128
#define N_ITEMS 200000
#define N_USERS 100000
#define TI 64    // items per score-kernel tile

#define INV_SQRT_D 0.088388347648318447f

// ---------------------------------------------------------------------------
// CSR build: histogram -> 3-kernel exclusive scan -> scatter pairs
// ---------------------------------------------------------------------------
__global__ __launch_bounds__(256) void hist_kernel(
    const int* __restrict__ dst, unsigned* __restrict__ counts, int E)
{
    int e = blockIdx.x * 256 + threadIdx.x;
    if (e < E) atomicAdd(&counts[dst[e]], 1u);
}

__global__ __launch_bounds__(256) void scan1_kernel(
    const unsigned* __restrict__ counts, unsigned* __restrict__ offsets,
    unsigned* __restrict__ blocksums, int n)
{
    __shared__ unsigned s[256];
    int tid = threadIdx.x;
    int i = blockIdx.x * 256 + tid;
    unsigned v = (i < n) ? counts[i] : 0u;
    s[tid] = v; __syncthreads();
    #pragma unroll
    for (int off = 1; off < 256; off <<= 1) {
        unsigned t = (tid >= off) ? s[tid - off] : 0u;
        __syncthreads();
        s[tid] += t;
        __syncthreads();
    }
    if (i < n) offsets[i] = s[tid] - v;          // exclusive within block
    if (tid == 255) blocksums[blockIdx.x] = s[255];
}

__global__ __launch_bounds__(1024) void scan2_kernel(
    unsigned* __restrict__ blocksums, int nb)
{
    __shared__ unsigned s[1024];
    int tid = threadIdx.x;
    unsigned v = (tid < nb) ? blocksums[tid] : 0u;
    s[tid] = v; __syncthreads();
    #pragma unroll
    for (int off = 1; off < 1024; off <<= 1) {
        unsigned t = (tid >= off) ? s[tid - off] : 0u;
        __syncthreads();
        s[tid] += t;
        __syncthreads();
    }
    if (tid < nb) blocksums[tid] = s[tid] - v;   // exclusive
}

__global__ __launch_bounds__(256) void scan3_kernel(
    unsigned* __restrict__ offsets, unsigned* __restrict__ cursor,
    const unsigned* __restrict__ blocksums, int n, unsigned Etot)
{
    int i = blockIdx.x * 256 + threadIdx.x;
    if (i < n) {
        unsigned o = offsets[i] + blocksums[blockIdx.x];
        offsets[i] = o;
        cursor[i] = o;
    }
    if (i == 0) offsets[n] = Etot;
}

__global__ __launch_bounds__(256) void scatter_kernel(
    const int* __restrict__ src, const int* __restrict__ dst,
    const float* __restrict__ val, unsigned* __restrict__ cursor,
    int2* __restrict__ pairs, int E)
{
    int e = blockIdx.x * 256 + threadIdx.x;
    if (e >= E) return;
    unsigned pos = atomicAdd(&cursor[dst[e]], 1u);
    pairs[pos] = make_int2(src[e], __float_as_int(val[e]));
}

// ---------------------------------------------------------------------------
// Gather spmm: one 32-lane group per dst row; register accumulation; one
// coalesced non-atomic float4 store per lane. No pre-zeroing needed.
// ---------------------------------------------------------------------------
__global__ __launch_bounds__(256) void gather_spmm_kernel(
    const unsigned* __restrict__ offsets, const int2* __restrict__ pairs,
    const float4* __restrict__ x4, float4* __restrict__ out4, int nrows)
{
    int row = blockIdx.x * 8 + (threadIdx.x >> 5);
    if (row >= nrows) return;
    int lane = threadIdx.x & 31;
    unsigned j = offsets[row], end = offsets[row + 1];
    float4 acc = make_float4(0.f, 0.f, 0.f, 0.f);
    for (; j + 2 <= end; j += 2) {
        int2 p0 = pairs[j];
        int2 p1 = pairs[j + 1];
        float4 a = x4[(size_t)p0.x * 32 + lane];
        float4 b = x4[(size_t)p1.x * 32 + lane];
        float v0 = __int_as_float(p0.y), v1 = __int_as_float(p1.y);
        acc.x = fmaf(v0, a.x, acc.x); acc.y = fmaf(v0, a.y, acc.y);
        acc.z = fmaf(v0, a.z, acc.z); acc.w = fmaf(v0, a.w, acc.w);
        acc.x = fmaf(v1, b.x, acc.x); acc.y = fmaf(v1, b.y, acc.y);
        acc.z = fmaf(v1, b.z, acc.z); acc.w = fmaf(v1, b.w, acc.w);
    }
    if (j < end) {
        int2 p0 = pairs[j];
        float4 a = x4[(size_t)p0.x * 32 + lane];
        float v0 = __int_as_float(p0.y);
        acc.x = fmaf(v0, a.x, acc.x); acc.y = fmaf(v0, a.y, acc.y);
        acc.z = fmaf(v0, a.z, acc.z); acc.w = fmaf(v0, a.w, acc.w);
    }
    out4[(size_t)row * 32 + lane] = acc;
}

// ---------------------------------------------------------------------------
// Fused gated-attention score + softmax + weighted-combine kernel, v3.
//   - lane = item (64 items/block); each wave owns a 32-column j-quarter.
//   - I[k][jbase..jbase+31] is wave-uniform -> s_load into SGPRs (scalar
//     cache pipe), zero vector-L1 traffic for the B operand.
//   - per k per wave: 1 ds_read_b32 (Tt[k][lane], conflict-free) + 32 FMA.
//   - Tt transposed [k][item], stride 65: reads conflict-free.
//   - x tile cached in 8 float4 registers across the 3 relations.
//   - LDS ~37 KB -> 4 blocks/CU.
// ---------------------------------------------------------------------------
__global__ __launch_bounds__(256, 4) void score_combine_kernel(
    const float4* __restrict__ x4,
    float4* __restrict__ nb0,                       // in: nb_in, out: neighbor
    const float4* __restrict__ nb1, const float4* __restrict__ nb2,
    const float* __restrict__ I0, const float* __restrict__ I1,
    const float* __restrict__ I2)
{
    __shared__ float Tt[D * 65];        // [k][item], stride 65: 33280 B
    __shared__ float Sred[3 * 4 * 64];  // per-rel per-wave partial sums
    __shared__ float Wl[TI * 3];        // softmax weights

    const int tid  = threadIdx.x;
    const int lane = tid & 63;
    const int wv   = __builtin_amdgcn_readfirstlane(tid >> 6);  // wave id 0..3
    const int ilo  = tid >> 5;          // 0..7
    const int dd4  = tid & 31;          // k-quad within row
    const int itemBase = blockIdx.x * TI;

    // cache the x tile in registers (8 float4 per thread, reused for 3 rels)
    float4 xr[8];
    #pragma unroll
    for (int it = 0; it < 8; ++it) {
        int il = it * 8 + ilo;
        xr[it] = x4[(size_t)(itemBase + il) * 32 + dd4];
    }

    const float4* nbs[3] = {(const float4*)nb0, nb1, nb2};
    const float*  Is[3]  = {I0, I1, I2};

    for (int rel = 0; rel < 3; ++rel) {
        __syncthreads();    // waves done reading Tt from previous rel
        // ---- stage Tt = x * nb, transposed [k][item] ----
        const float4* nbp = nbs[rel];
        #pragma unroll
        for (int it = 0; it < 8; ++it) {
            int il = it * 8 + ilo;
            float4 b = nbp[(size_t)(itemBase + il) * 32 + dd4];
            float4 a = xr[it];
            int base = (dd4 * 4) * 65 + il;
            Tt[base]       = a.x * b.x;
            Tt[base + 65]  = a.y * b.y;
            Tt[base + 130] = a.z * b.z;
            Tt[base + 195] = a.w * b.w;
        }
        __syncthreads();

        // ---- h(item=lane, j in wave's quarter) = sum_k t[k]*I[k][j] ----
        const float4* Iw4 = (const float4*)Is[rel] + wv * 8;   // wave-uniform
        float4 acc[8];
        #pragma unroll
        for (int c = 0; c < 8; ++c) acc[c] = make_float4(0.f, 0.f, 0.f, 0.f);

        #pragma unroll 2
        for (int k = 0; k < D; ++k) {
            float tv = Tt[k * 65 + lane];
            #pragma unroll
            for (int c = 0; c < 8; ++c) {
                float4 iv = Iw4[k * 32 + c];     // s_load: wave-uniform addr
                acc[c].x = fmaf(tv, iv.x, acc[c].x);
                acc[c].y = fmaf(tv, iv.y, acc[c].y);
                acc[c].z = fmaf(tv, iv.z, acc[c].z);
                acc[c].w = fmaf(tv, iv.w, acc[c].w);
            }
        }

        // ---- leaky + partial row-sum over this wave's 32 columns ----
        float s = 0.f;
        #pragma unroll
        for (int c = 0; c < 8; ++c) {
            s += fmaxf(acc[c].x, 0.2f * acc[c].x);
            s += fmaxf(acc[c].y, 0.2f * acc[c].y);
            s += fmaxf(acc[c].z, 0.2f * acc[c].z);
            s += fmaxf(acc[c].w, 0.2f * acc[c].w);
        }
        Sred[rel * 256 + wv * 64 + lane] = s;
    }
    __syncthreads();

    // ---- reduce wave partials, softmax over relations -> LDS weights ----
    if (tid < TI) {
        float sr[3];
        #pragma unroll
        for (int r = 0; r < 3; ++r)
            sr[r] = (Sred[r * 256 + tid] + Sred[r * 256 + 64 + tid] +
                     Sred[r * 256 + 128 + tid] + Sred[r * 256 + 192 + tid])
                    * INV_SQRT_D;
        float m = fmaxf(sr[0], fmaxf(sr[1], sr[2]));
        float e0 = expf(sr[0] - m), e1 = expf(sr[1] - m), e2 = expf(sr[2] - m);
        float inv = 1.f / (e0 + e1 + e2);
        Wl[tid * 3 + 0] = e0 * inv;
        Wl[tid * 3 + 1] = e1 * inv;
        Wl[tid * 3 + 2] = e2 * inv;
    }
    __syncthreads();

    // ---- fused weighted combine, in place over nb0 ----
    #pragma unroll
    for (int it = 0; it < 8; ++it) {
        int il = it * 8 + ilo;
        size_t g = (size_t)(itemBase + il) * 32 + dd4;
        float w0 = Wl[il * 3 + 0], w1 = Wl[il * 3 + 1], w2 = Wl[il * 3 + 2];
        float4 a = nb0[g], b = nb1[g], c = nb2[g];
        float4 r;
        r.x = fmaf(w0, a.x, fmaf(w1, b.x, w2 * c.x));
        r.y = fmaf(w0, a.y, fmaf(w1, b.y, w2 * c.y));
        r.z = fmaf(w0, a.z, fmaf(w1, b.z, w2 * c.z));
        r.w = fmaf(w0, a.w, fmaf(w1, b.w, w2 * c.w));
        nb0[g] = r;
    }
}

extern "C" void kernel_launch(void* const* d_in, const int* in_sizes, int n_in,
                              void* d_out, int out_size, void* d_ws, size_t ws_size,
                              hipStream_t stream) {
    const float* x       = (const float*)d_in[1];
    const int*   src0    = (const int*)d_in[2];
    const int*   dst0    = (const int*)d_in[3];
    const float* val0    = (const float*)d_in[4];
    const int*   src1    = (const int*)d_in[5];
    const int*   dst1    = (const int*)d_in[6];
    const float* val1    = (const float*)d_in[7];
    const int*   src2    = (const int*)d_in[8];
    const int*   dst2    = (const int*)d_in[9];
    const float* val2    = (const float*)d_in[10];
    const int*   src_ui  = (const int*)d_in[11];
    const int*   dst_ui  = (const int*)d_in[12];
    const float* val_ui  = (const float*)d_in[13];
    const float* I0      = (const float*)d_in[14];
    const float* I1      = (const float*)d_in[15];
    const float* I2      = (const float*)d_in[16];

    const int E_ii = in_sizes[2];
    const int E_ui = in_sizes[11];

    float* u_emb = (float*)d_out;                          // [N_USERS*D], written last
    float* nb0   = (float*)d_out + (size_t)N_USERS * D;    // neighbor slot doubles as nb_in

    // workspace layout
    float*    nb1       = (float*)d_ws;                                  // 25.6M floats
    float*    nb2       = nb1 + (size_t)N_ITEMS * D;                     // 25.6M floats
    unsigned* cc        = (unsigned*)(nb2 + (size_t)N_ITEMS * D);        // counts/cursor [N_ITEMS]
    unsigned* offsets   = cc + N_ITEMS;                                  // [N_ITEMS+1]
    unsigned* blocksums = offsets + N_ITEMS + 1;                         // [1024]
    uintptr_t pu        = ((uintptr_t)(blocksums + 1024) + 15) & ~(uintptr_t)15;
    int2*     pairs_ui  = (int2*)pu;                                     // [E_ui]
    // ii pairs live in the u_emb output region (free until the final ui gather)
    int2*     pairs_ii  = (int2*)d_out;                                  // 25.6 MB <= 51.2 MB region

    auto build_and_gather = [&](const int* src, const int* dst, const float* val,
                                int E, int nrows, int2* pairs, float* out) {
        hipMemsetAsync(cc, 0, (size_t)nrows * sizeof(unsigned), stream);
        int gE = (E + 255) / 256;
        int gN = (nrows + 255) / 256;
        hist_kernel<<<gE, 256, 0, stream>>>(dst, cc, E);
        scan1_kernel<<<gN, 256, 0, stream>>>(cc, offsets, blocksums, nrows);
        scan2_kernel<<<1, 1024, 0, stream>>>(blocksums, gN);
        scan3_kernel<<<gN, 256, 0, stream>>>(offsets, cc, blocksums, nrows, (unsigned)E);
        scatter_kernel<<<gE, 256, 0, stream>>>(src, dst, val, cc, pairs, E);
        gather_spmm_kernel<<<(nrows + 7) / 8, 256, 0, stream>>>(
            offsets, pairs, (const float4*)x, (float4*)out, nrows);
    };

    // item-item relations (pairs scratch in u_emb region)
    build_and_gather(src0, dst0, val0, E_ii, N_ITEMS, pairs_ii, nb0);
    build_and_gather(src1, dst1, val1, E_ii, N_ITEMS, pairs_ii, nb1);
    build_and_gather(src2, dst2, val2, E_ii, N_ITEMS, pairs_ii, nb2);

    // fused score + softmax + combine (in-place over nb0 == neighbor output)
    score_combine_kernel<<<N_ITEMS / TI, 256, 0, stream>>>(
        (const float4*)x, (float4*)nb0, (const float4*)nb1, (const float4*)nb2,
        I0, I1, I2);

    // user-item last (writes u_emb region, whose pairs scratch is now dead)
    build_and_gather(src_ui, dst_ui, val_ui, E_ui, N_USERS, pairs_ui, u_emb);
}